// Round 10
// baseline (17.918 us; speedup 1.0000x reference)
//
#include <hip/hip_runtime.h>

// Separable RBF interpolation. Grid is a 128x128 tensor-product lattice:
// w(m,n) = wy(my,n)*wx(mx,n);  D[my][mx][ch] = sum_k wy*wx*Y[k][ch], Y[k][0]=1.
// Block = (batch, 32 my, 16 mx); 16 waves split K=2048 (128 each).
// Each wave computes TWO 16x16 my-tiles (WM=2): y/x LDS reads and all 9
// B-fragments are shared across both tiles (halves LDS-BW per output).
// Fragments computed in registers (broadcast LDS reads + exp2). Fixed-order
// 8-slot reduce (deterministic), fully parallel normalize+store.

typedef float  f32x4 __attribute__((ext_vector_type(4)));
typedef __fp16 half8  __attribute__((ext_vector_type(8)));
typedef __fp16 half2t __attribute__((ext_vector_type(2)));

constexpr int B_  = 8;
constexpr int NC  = 2048;
constexpr int M_  = 128 * 128;
constexpr int BLK = 1024;         // 16 waves
constexpr int KW  = 128;          // k-range per wave
constexpr int LDHY = NC + 8;      // padded f16 row stride for y (2056)

// LDS pool carve (bytes)
constexpr int OFF_SXT = 0;                         // 2048 f32 (s*x.x)
constexpr int OFF_SYT = OFF_SXT + NC * 4;          // 8192  (s*x.y)
constexpr int OFF_SYS = OFF_SYT + NC * 4;          // 16384 y f16 [8][LDHY]
constexpr int OFF_SG  = OFF_SYS + 8 * LDHY * 2;    // 49280 (48 floats)
// epilogue alias (everything above is dead): 8 slots x [2][9][256] f32
constexpr int SLOT_F  = 2 * 9 * 256;               // 4608 floats per slot
constexpr int POOL_B  = 8 * SLOT_F * 4;            // 147456 B (1 block/CU)

__global__ __launch_bounds__(BLK) void rbf_sep(
    const float* __restrict__ x_c,
    const float* __restrict__ y_c,
    const float* __restrict__ gp,
    const float* __restrict__ sigma_p,
    float* __restrict__ out)
{
    __shared__ __align__(16) char pool[POOL_B];
    float*  sxt = (float*)(pool + OFF_SXT);
    float*  syt = (float*)(pool + OFF_SYT);
    __fp16* sys = (__fp16*)(pool + OFF_SYS);
    float*  sg  = (float*)(pool + OFF_SG);

    const int tid  = (int)threadIdx.x;
    const int lane = tid & 63;
    const int w    = tid >> 6;       // wave 0..15
    const int q    = lane >> 4;
    const int cl   = lane & 15;

    const int bid = blockIdx.x;
    const int b   = bid >> 5;                 // 32 blocks per batch
    const int myg = (bid >> 3) & 3;
    const int mxg = bid & 7;
    const int my0 = myg * 32;
    const int mx0 = mxg * 16;

    const float sigma = sigma_p[0];
    const float s = __builtin_sqrtf(0.72134752044448170f) / sigma;

    if (tid < 32)      sg[tid] = s * gp[(my0 + tid) * 256 + 1];
    else if (tid < 48) sg[tid] = s * gp[(mx0 + (tid - 32)) * 2];

    // stage x (scaled SoA f32) and y (f16 [ch][k]) for the full K range
    const float2* xb = (const float2*)x_c + (size_t)b * NC;
    const float4* yb = (const float4*)y_c + (size_t)b * NC * 2;
    for (int it = tid; it < NC; it += BLK) {
        const float2 v = xb[it];
        sxt[it] = s * v.x;
        syt[it] = s * v.y;
        const float4 y0 = yb[(size_t)it * 2];
        const float4 y1 = yb[(size_t)it * 2 + 1];
        __fp16* yw = sys + it;
        yw[0 * LDHY] = (__fp16)y0.x;
        yw[1 * LDHY] = (__fp16)y0.y;
        yw[2 * LDHY] = (__fp16)y0.z;
        yw[3 * LDHY] = (__fp16)y0.w;
        yw[4 * LDHY] = (__fp16)y1.x;
        yw[5 * LDHY] = (__fp16)y1.y;
        yw[6 * LDHY] = (__fp16)y1.z;
        yw[7 * LDHY] = (__fp16)y1.w;
    }
    __syncthreads();

    const float sgy0 = sg[cl];         // my-tile 0: rows my0 + cl
    const float sgy1 = sg[16 + cl];    // my-tile 1: rows my0 + 16 + cl
    const float sgxr = sg[32 + cl];    // mx: cols mx0 + cl

    f32x4 acc[2][9];
#pragma unroll
    for (int t = 0; t < 2; ++t)
#pragma unroll
        for (int c = 0; c < 9; ++c) acc[t][c] = (f32x4)0.0f;

    // main loop: wave covers K window [w*KW, (w+1)*KW), 4 steps of 32
    const int kbase = w * KW;
#pragma unroll 2
    for (int ks = 0; ks < KW / 32; ++ks) {
        const int kq = kbase + ks * 32 + q * 8;

        const f32x4 ya0 = *(const f32x4*)(syt + kq);
        const f32x4 ya1 = *(const f32x4*)(syt + kq + 4);
        const f32x4 xa0 = *(const f32x4*)(sxt + kq);
        const f32x4 xa1 = *(const f32x4*)(sxt + kq + 4);

        // A-fragment wy for my-tile 0
        const f32x4 y0e0 = ya0 - sgy0, y0e1 = ya1 - sgy0;
        const f32x4 y0m0 = y0e0 * y0e0, y0m1 = y0e1 * y0e1;
        const half2t p00 = __builtin_amdgcn_cvt_pkrtz(
            __builtin_amdgcn_exp2f(-y0m0.x), __builtin_amdgcn_exp2f(-y0m0.y));
        const half2t p01 = __builtin_amdgcn_cvt_pkrtz(
            __builtin_amdgcn_exp2f(-y0m0.z), __builtin_amdgcn_exp2f(-y0m0.w));
        const half2t p02 = __builtin_amdgcn_cvt_pkrtz(
            __builtin_amdgcn_exp2f(-y0m1.x), __builtin_amdgcn_exp2f(-y0m1.y));
        const half2t p03 = __builtin_amdgcn_cvt_pkrtz(
            __builtin_amdgcn_exp2f(-y0m1.z), __builtin_amdgcn_exp2f(-y0m1.w));
        const half8 af0 = (half8){p00.x, p00.y, p01.x, p01.y, p02.x, p02.y, p03.x, p03.y};

        // A-fragment wy for my-tile 1
        const f32x4 y1e0 = ya0 - sgy1, y1e1 = ya1 - sgy1;
        const f32x4 y1m0 = y1e0 * y1e0, y1m1 = y1e1 * y1e1;
        const half2t p10 = __builtin_amdgcn_cvt_pkrtz(
            __builtin_amdgcn_exp2f(-y1m0.x), __builtin_amdgcn_exp2f(-y1m0.y));
        const half2t p11 = __builtin_amdgcn_cvt_pkrtz(
            __builtin_amdgcn_exp2f(-y1m0.z), __builtin_amdgcn_exp2f(-y1m0.w));
        const half2t p12 = __builtin_amdgcn_cvt_pkrtz(
            __builtin_amdgcn_exp2f(-y1m1.x), __builtin_amdgcn_exp2f(-y1m1.y));
        const half2t p13 = __builtin_amdgcn_cvt_pkrtz(
            __builtin_amdgcn_exp2f(-y1m1.z), __builtin_amdgcn_exp2f(-y1m1.w));
        const half8 af1 = (half8){p10.x, p10.y, p11.x, p11.y, p12.x, p12.y, p13.x, p13.y};

        // B-fragment wx (shared across both my-tiles)
        const f32x4 xe0 = xa0 - sgxr, xe1 = xa1 - sgxr;
        const f32x4 xm0 = xe0 * xe0,   xm1 = xe1 * xe1;
        const half2t b0 = __builtin_amdgcn_cvt_pkrtz(
            __builtin_amdgcn_exp2f(-xm0.x), __builtin_amdgcn_exp2f(-xm0.y));
        const half2t b1 = __builtin_amdgcn_cvt_pkrtz(
            __builtin_amdgcn_exp2f(-xm0.z), __builtin_amdgcn_exp2f(-xm0.w));
        const half2t b2 = __builtin_amdgcn_cvt_pkrtz(
            __builtin_amdgcn_exp2f(-xm1.x), __builtin_amdgcn_exp2f(-xm1.y));
        const half2t b3 = __builtin_amdgcn_cvt_pkrtz(
            __builtin_amdgcn_exp2f(-xm1.z), __builtin_amdgcn_exp2f(-xm1.w));
        const half8 bx = (half8){b0.x, b0.y, b1.x, b1.y, b2.x, b2.y, b3.x, b3.y};

        acc[0][0] = __builtin_amdgcn_mfma_f32_16x16x32_f16(af0, bx, acc[0][0], 0, 0, 0);
        acc[1][0] = __builtin_amdgcn_mfma_f32_16x16x32_f16(af1, bx, acc[1][0], 0, 0, 0);
        const __fp16* yp = sys + kq;
#pragma unroll
        for (int c = 0; c < 8; ++c) {
            const half8 yf  = *(const half8*)(yp + c * LDHY);
            const half8 bxy = bx * yf;   // shared B-fragment for both tiles
            acc[0][c + 1] = __builtin_amdgcn_mfma_f32_16x16x32_f16(af0, bxy, acc[0][c + 1], 0, 0, 0);
            acc[1][c + 1] = __builtin_amdgcn_mfma_f32_16x16x32_f16(af1, bxy, acc[1][c + 1], 0, 0, 0);
        }
    }

    // ---- reduce: slot_s = acc_{s+8} + acc_s; final fixed-order pairwise ----
    __syncthreads();                       // tiles dead; alias slot bufs
    float* slots = (float*)pool;           // [8][2][9][256]
    if (w >= 8) {
        float* rb = slots + (w - 8) * SLOT_F;
#pragma unroll
        for (int t = 0; t < 2; ++t)
#pragma unroll
            for (int c = 0; c < 9; ++c)
#pragma unroll
                for (int r = 0; r < 4; ++r)
                    rb[t * 2304 + c * 256 + (q * 4 + r) * 16 + cl] = acc[t][c][r];
    }
    __syncthreads();
    if (w < 8) {
        float* rb = slots + w * SLOT_F;
#pragma unroll
        for (int t = 0; t < 2; ++t)
#pragma unroll
            for (int c = 0; c < 9; ++c)
#pragma unroll
                for (int r = 0; r < 4; ++r) {
                    const int idx = t * 2304 + c * 256 + (q * 4 + r) * 16 + cl;
                    rb[idx] = rb[idx] + acc[t][c][r];   // acc_{w+8} + acc_w
                }
    }
    __syncthreads();

    // parallel final sum + normalize + store: 2t x 9ch x 16my x 4quads = 1152
    float* ob = out + (size_t)b * 9 * M_;
    for (int it = tid; it < 1152; it += BLK) {
        const int t  = it / 576;
        const int rr = it % 576;
        const int c  = rr >> 6;
        const int my = (rr & 63) >> 2;
        const int xq = rr & 3;
        const int base  = t * 2304 + c * 256 + my * 16 + xq * 4;
        const int dbase = t * 2304 +           my * 16 + xq * 4;

        #define SUM8(off) ( (*(const f32x4*)(slots + 0*SLOT_F + (off)) + *(const f32x4*)(slots + 1*SLOT_F + (off))) \
                          + (*(const f32x4*)(slots + 2*SLOT_F + (off)) + *(const f32x4*)(slots + 3*SLOT_F + (off))) \
                          + ((*(const f32x4*)(slots + 4*SLOT_F + (off)) + *(const f32x4*)(slots + 5*SLOT_F + (off))) \
                          +  (*(const f32x4*)(slots + 6*SLOT_F + (off)) + *(const f32x4*)(slots + 7*SLOT_F + (off)))) )
        const f32x4 v = SUM8(base);
        f32x4 o;
        if (c == 0) {
            o = v;
        } else {
            const f32x4 d = SUM8(dbase);
            o.x = v.x * __builtin_amdgcn_rcpf(d.x + 1e-5f);
            o.y = v.y * __builtin_amdgcn_rcpf(d.y + 1e-5f);
            o.z = v.z * __builtin_amdgcn_rcpf(d.z + 1e-5f);
            o.w = v.w * __builtin_amdgcn_rcpf(d.w + 1e-5f);
        }
        #undef SUM8
        *(f32x4*)(ob + (size_t)c * M_ + (size_t)(my0 + t * 16 + my) * 128 + mx0 + xq * 4) = o;
    }
}

extern "C" void kernel_launch(void* const* d_in, const int* in_sizes, int n_in,
                              void* d_out, int out_size, void* d_ws, size_t ws_size,
                              hipStream_t stream) {
    const float* x_c   = (const float*)d_in[0];
    const float* y_c   = (const float*)d_in[1];
    const float* gp    = (const float*)d_in[2];
    const float* sigma = (const float*)d_in[3];
    float* out = (float*)d_out;

    dim3 grid(B_ * 32);      // 256 blocks: 8 batches x 4 my-groups x 8 mx-groups
    dim3 block(BLK);
    rbf_sep<<<grid, block, 0, stream>>>(x_c, y_c, gp, sigma, out);
}

// Round 11
// 17.651 us; speedup vs baseline: 1.0151x; 1.0151x over previous
//
#include <hip/hip_runtime.h>

// Separable RBF interpolation. Grid is a 128x128 tensor-product lattice:
// w(m,n) = wy(my,n)*wx(mx,n);  D[my][mx][ch] = sum_k wy*wx*Y[k][ch], Y[k][0]=1.
// Block = (batch, 16 my, 16 mx); 8 waves split each K-chunk (128 k per wave
// per chunk). K=2048 split into 2 chunks with double-buffered LDS staging:
// chunk1's global loads are issued before chunk0's compute (latency hidden).
// Fragments computed in registers (broadcast LDS reads + exp2). Fixed-order
// 4-slot reduce (deterministic), fully parallel normalize+store.

typedef float  f32x4 __attribute__((ext_vector_type(4)));
typedef __fp16 half8  __attribute__((ext_vector_type(8)));
typedef __fp16 half2t __attribute__((ext_vector_type(2)));

constexpr int B_  = 8;
constexpr int NC  = 2048;
constexpr int M_  = 128 * 128;
constexpr int BLK = 512;          // 8 waves
constexpr int CH  = 1024;         // k per chunk
constexpr int LDHY = CH + 8;      // padded f16 row stride (1032)

// per-buffer LDS carve (bytes)
constexpr int OFF_SXT = 0;                      // CH f32 = 4096 (s*x.x)
constexpr int OFF_SYT = OFF_SXT + CH * 4;       // 4096   (s*x.y)
constexpr int OFF_SYS = OFF_SYT + CH * 4;       // 8192   y f16 [8][LDHY] = 16512
constexpr int BUF_B   = OFF_SYS + 8 * LDHY * 2; // 24704 per buffer
constexpr int OFF_SG  = 2 * BUF_B;              // 49408 (48 floats)
constexpr int POOL_B  = OFF_SG + 48 * 4;        // 49600 B
// epilogue alias (buffers dead, barrier-separated): 4 slots x [9][256] f32
constexpr int SLOT_F  = 9 * 256;                // 36864 B total

__global__ __launch_bounds__(BLK) void rbf_sep(
    const float* __restrict__ x_c,
    const float* __restrict__ y_c,
    const float* __restrict__ gp,
    const float* __restrict__ sigma_p,
    float* __restrict__ out)
{
    __shared__ __align__(16) char pool[POOL_B];
    float* sg = (float*)(pool + OFF_SG);

    const int tid  = (int)threadIdx.x;
    const int lane = tid & 63;
    const int w    = tid >> 6;       // wave 0..7
    const int q    = lane >> 4;
    const int cl   = lane & 15;

    const int bid = blockIdx.x;
    const int b   = bid >> 6;                 // 64 blocks per batch
    const int myg = (bid >> 3) & 7;
    const int mxg = bid & 7;
    const int my0 = myg * 16;
    const int mx0 = mxg * 16;

    const float sigma = sigma_p[0];
    const float s = __builtin_sqrtf(0.72134752044448170f) / sigma;

    if (tid < 16)      sg[tid] = s * gp[(my0 + tid) * 256 + 1];
    else if (tid < 32) sg[tid] = s * gp[(mx0 + (tid - 16)) * 2];

    // global pointers; thread t owns k = c*CH + 2t, 2t+1
    const float4* xb4 = (const float4*)(x_c + (size_t)b * NC * 2);   // 1024 float4
    const float4* yb4 = (const float4*)(y_c + (size_t)b * NC * 8);   // 4096 float4

    // ---- load chunk 0 ----
    float4 xv0 = xb4[tid];
    float4 ya0g = yb4[4 * tid + 0];
    float4 yb0g = yb4[4 * tid + 1];
    float4 yc0g = yb4[4 * tid + 2];
    float4 yd0g = yb4[4 * tid + 3];

    // ---- stage chunk 0 into buffer 0 ----
    {
        float*  sxtb = (float*)(pool + OFF_SXT);
        float*  sytb = (float*)(pool + OFF_SYT);
        __fp16* sysb = (__fp16*)(pool + OFF_SYS);
        *(float2*)(sxtb + 2 * tid) = (float2){s * xv0.x, s * xv0.z};
        *(float2*)(sytb + 2 * tid) = (float2){s * xv0.y, s * xv0.w};
        // k=2t channels: ya0g(0-3), yb0g(4-7); k=2t+1: yc0g(0-3), yd0g(4-7)
        *(half2t*)(sysb + 0 * LDHY + 2 * tid) = (half2t){(__fp16)ya0g.x, (__fp16)yc0g.x};
        *(half2t*)(sysb + 1 * LDHY + 2 * tid) = (half2t){(__fp16)ya0g.y, (__fp16)yc0g.y};
        *(half2t*)(sysb + 2 * LDHY + 2 * tid) = (half2t){(__fp16)ya0g.z, (__fp16)yc0g.z};
        *(half2t*)(sysb + 3 * LDHY + 2 * tid) = (half2t){(__fp16)ya0g.w, (__fp16)yc0g.w};
        *(half2t*)(sysb + 4 * LDHY + 2 * tid) = (half2t){(__fp16)yb0g.x, (__fp16)yd0g.x};
        *(half2t*)(sysb + 5 * LDHY + 2 * tid) = (half2t){(__fp16)yb0g.y, (__fp16)yd0g.y};
        *(half2t*)(sysb + 6 * LDHY + 2 * tid) = (half2t){(__fp16)yb0g.z, (__fp16)yd0g.z};
        *(half2t*)(sysb + 7 * LDHY + 2 * tid) = (half2t){(__fp16)yb0g.w, (__fp16)yd0g.w};
    }
    __syncthreads();

    const float sgy_r = sg[cl];
    const float sgx_r = sg[16 + cl];

    // ---- issue chunk 1 global loads (latency hides under chunk-0 compute) ----
    float4 xv1 = xb4[512 + tid];
    float4 ya1g = yb4[2048 + 4 * tid + 0];
    float4 yb1g = yb4[2048 + 4 * tid + 1];
    float4 yc1g = yb4[2048 + 4 * tid + 2];
    float4 yd1g = yb4[2048 + 4 * tid + 3];

    f32x4 acc[9];
#pragma unroll
    for (int c = 0; c < 9; ++c) acc[c] = (f32x4)0.0f;

    // ---- compute a chunk: wave covers [w*128, w*128+128), 4 steps of 32 ----
#define COMPUTE_CHUNK(BUFOFF)                                                     \
    {                                                                             \
        const float*  sxtb = (const float*)(pool + (BUFOFF) + OFF_SXT);           \
        const float*  sytb = (const float*)(pool + (BUFOFF) + OFF_SYT);           \
        const __fp16* sysb = (const __fp16*)(pool + (BUFOFF) + OFF_SYS);          \
        _Pragma("unroll")                                                         \
        for (int ks = 0; ks < 4; ++ks) {                                          \
            const int kq = w * 128 + ks * 32 + q * 8;                             \
            const f32x4 ya0 = *(const f32x4*)(sytb + kq);                         \
            const f32x4 ya1 = *(const f32x4*)(sytb + kq + 4);                     \
            const f32x4 xa0 = *(const f32x4*)(sxtb + kq);                         \
            const f32x4 xa1 = *(const f32x4*)(sxtb + kq + 4);                     \
            const f32x4 ye0 = ya0 - sgy_r, ye1 = ya1 - sgy_r;                     \
            const f32x4 ym0 = ye0 * ye0,   ym1 = ye1 * ye1;                       \
            const half2t a0 = __builtin_amdgcn_cvt_pkrtz(                         \
                __builtin_amdgcn_exp2f(-ym0.x), __builtin_amdgcn_exp2f(-ym0.y));  \
            const half2t a1 = __builtin_amdgcn_cvt_pkrtz(                         \
                __builtin_amdgcn_exp2f(-ym0.z), __builtin_amdgcn_exp2f(-ym0.w));  \
            const half2t a2 = __builtin_amdgcn_cvt_pkrtz(                         \
                __builtin_amdgcn_exp2f(-ym1.x), __builtin_amdgcn_exp2f(-ym1.y));  \
            const half2t a3 = __builtin_amdgcn_cvt_pkrtz(                         \
                __builtin_amdgcn_exp2f(-ym1.z), __builtin_amdgcn_exp2f(-ym1.w));  \
            const half8 af = (half8){a0.x, a0.y, a1.x, a1.y, a2.x, a2.y, a3.x, a3.y}; \
            const f32x4 xe0 = xa0 - sgx_r, xe1 = xa1 - sgx_r;                     \
            const f32x4 xm0 = xe0 * xe0,   xm1 = xe1 * xe1;                       \
            const half2t b0 = __builtin_amdgcn_cvt_pkrtz(                         \
                __builtin_amdgcn_exp2f(-xm0.x), __builtin_amdgcn_exp2f(-xm0.y));  \
            const half2t b1 = __builtin_amdgcn_cvt_pkrtz(                         \
                __builtin_amdgcn_exp2f(-xm0.z), __builtin_amdgcn_exp2f(-xm0.w));  \
            const half2t b2 = __builtin_amdgcn_cvt_pkrtz(                         \
                __builtin_amdgcn_exp2f(-xm1.x), __builtin_amdgcn_exp2f(-xm1.y));  \
            const half2t b3 = __builtin_amdgcn_cvt_pkrtz(                         \
                __builtin_amdgcn_exp2f(-xm1.z), __builtin_amdgcn_exp2f(-xm1.w));  \
            const half8 bx = (half8){b0.x, b0.y, b1.x, b1.y, b2.x, b2.y, b3.x, b3.y}; \
            acc[0] = __builtin_amdgcn_mfma_f32_16x16x32_f16(af, bx, acc[0], 0, 0, 0); \
            const __fp16* yp = sysb + kq;                                         \
            _Pragma("unroll")                                                     \
            for (int c = 0; c < 8; ++c) {                                         \
                const half8 yf = *(const half8*)(yp + c * LDHY);                  \
                acc[c + 1] = __builtin_amdgcn_mfma_f32_16x16x32_f16(af, bx * yf, acc[c + 1], 0, 0, 0); \
            }                                                                     \
        }                                                                         \
    }

    COMPUTE_CHUNK(0)

    // ---- stage chunk 1 into buffer 1 (writes disjoint from buffer 0) ----
    {
        float*  sxtb = (float*)(pool + BUF_B + OFF_SXT);
        float*  sytb = (float*)(pool + BUF_B + OFF_SYT);
        __fp16* sysb = (__fp16*)(pool + BUF_B + OFF_SYS);
        *(float2*)(sxtb + 2 * tid) = (float2){s * xv1.x, s * xv1.z};
        *(float2*)(sytb + 2 * tid) = (float2){s * xv1.y, s * xv1.w};
        *(half2t*)(sysb + 0 * LDHY + 2 * tid) = (half2t){(__fp16)ya1g.x, (__fp16)yc1g.x};
        *(half2t*)(sysb + 1 * LDHY + 2 * tid) = (half2t){(__fp16)ya1g.y, (__fp16)yc1g.y};
        *(half2t*)(sysb + 2 * LDHY + 2 * tid) = (half2t){(__fp16)ya1g.z, (__fp16)yc1g.z};
        *(half2t*)(sysb + 3 * LDHY + 2 * tid) = (half2t){(__fp16)ya1g.w, (__fp16)yc1g.w};
        *(half2t*)(sysb + 4 * LDHY + 2 * tid) = (half2t){(__fp16)yb1g.x, (__fp16)yd1g.x};
        *(half2t*)(sysb + 5 * LDHY + 2 * tid) = (half2t){(__fp16)yb1g.y, (__fp16)yd1g.y};
        *(half2t*)(sysb + 6 * LDHY + 2 * tid) = (half2t){(__fp16)yb1g.z, (__fp16)yd1g.z};
        *(half2t*)(sysb + 7 * LDHY + 2 * tid) = (half2t){(__fp16)yb1g.w, (__fp16)yd1g.w};
    }
    __syncthreads();

    COMPUTE_CHUNK(BUF_B)
#undef COMPUTE_CHUNK

    // ---- flat reduce: slot_s = acc_{s+4} + acc_s; final = (s0+s1)+(s2+s3) ----
    __syncthreads();                       // buffers dead; alias slot bufs
    float* slots = (float*)pool;           // [4][9][256]
    if (w >= 4) {
        float* rb = slots + (w - 4) * SLOT_F;
#pragma unroll
        for (int c = 0; c < 9; ++c)
#pragma unroll
            for (int r = 0; r < 4; ++r)
                rb[c * 256 + (q * 4 + r) * 16 + cl] = acc[c][r];
    }
    __syncthreads();
    if (w < 4) {
        float* rb = slots + w * SLOT_F;
#pragma unroll
        for (int c = 0; c < 9; ++c)
#pragma unroll
            for (int r = 0; r < 4; ++r) {
                const int idx = c * 256 + (q * 4 + r) * 16 + cl;
                rb[idx] = rb[idx] + acc[c][r];   // acc_{w+4} + acc_w (fixed order)
            }
    }
    __syncthreads();

    // final 4-way sum + normalize + store, fully parallel over 256 m's
    if (tid < 256) {
        float* ob = out + (size_t)b * 9 * M_;
        const int my = tid >> 4, mx = tid & 15;
        const size_t mo = (size_t)(my0 + my) * 128 + mx0 + mx;
        float v[9];
#pragma unroll
        for (int c = 0; c < 9; ++c) {
            const int idx = c * 256 + tid;
            v[c] = (slots[idx] + slots[SLOT_F + idx]) +
                   (slots[2 * SLOT_F + idx] + slots[3 * SLOT_F + idx]);
        }
        const float inv = __builtin_amdgcn_rcpf(v[0] + 1e-5f);
        ob[mo] = v[0];
#pragma unroll
        for (int c = 1; c < 9; ++c)
            ob[(size_t)c * M_ + mo] = v[c] * inv;
    }
}

extern "C" void kernel_launch(void* const* d_in, const int* in_sizes, int n_in,
                              void* d_out, int out_size, void* d_ws, size_t ws_size,
                              hipStream_t stream) {
    const float* x_c   = (const float*)d_in[0];
    const float* y_c   = (const float*)d_in[1];
    const float* gp    = (const float*)d_in[2];
    const float* sigma = (const float*)d_in[3];
    float* out = (float*)d_out;

    dim3 grid(B_ * 64);      // 512 blocks: 8 batches x 8 my-groups x 8 mx-groups
    dim3 block(BLK);
    rbf_sep<<<grid, block, 0, stream>>>(x_c, y_c, gp, sigma, out);
}

// Round 12
// 16.804 us; speedup vs baseline: 1.0663x; 1.0504x over previous
//
#include <hip/hip_runtime.h>

// Separable RBF interpolation. Grid is a 128x128 tensor-product lattice:
// w(m,n) = wy(my,n)*wx(mx,n);  D[my][mx][ch] = sum_k wy*wx*Y[k][ch], Y[k][0]=1.
// Block = (batch, 32 my, 16 mx); 8 waves split K=2048 (256 each).
// WM=2: each wave computes TWO 16x16 my-tiles; coord/y LDS reads and the 9
// B-fragments are shared across both tiles (halves LDS-read instrs per output).
// __launch_bounds__(512,2) -> 256-VGPR budget, no spill (R9's confound).
// Fixed-order 4-slot reduce (deterministic), fully parallel normalize+store.

typedef float  f32x4 __attribute__((ext_vector_type(4)));
typedef __fp16 half8  __attribute__((ext_vector_type(8)));
typedef __fp16 half2t __attribute__((ext_vector_type(2)));

constexpr int B_  = 8;
constexpr int NC  = 2048;
constexpr int M_  = 128 * 128;
constexpr int BLK = 512;          // 8 waves
constexpr int KW  = 256;          // k-range per wave
constexpr int LDHY = NC + 8;      // padded f16 row stride for y (2056)

// LDS pool carve (bytes)
constexpr int OFF_SXT = 0;                         // 2048 f32 (s*x.x)
constexpr int OFF_SYT = OFF_SXT + NC * 4;          // 8192  (s*x.y)
constexpr int OFF_SYS = OFF_SYT + NC * 4;          // 16384 y f16 [8][LDHY]
constexpr int OFF_SG  = OFF_SYS + 8 * LDHY * 2;    // 49280 (48 floats)
// epilogue alias (tiles dead, barrier-separated): 4 slots x [2][9][256] f32
constexpr int SLOT_F  = 2 * 9 * 256;               // 4608 floats / slot
constexpr int POOL_B  = 4 * SLOT_F * 4;            // 73728 B (1 block/CU grid)

__global__ __launch_bounds__(BLK, 2) void rbf_sep(
    const float* __restrict__ x_c,
    const float* __restrict__ y_c,
    const float* __restrict__ gp,
    const float* __restrict__ sigma_p,
    float* __restrict__ out)
{
    __shared__ __align__(16) char pool[POOL_B];
    float*  sxt = (float*)(pool + OFF_SXT);
    float*  syt = (float*)(pool + OFF_SYT);
    __fp16* sys = (__fp16*)(pool + OFF_SYS);
    float*  sg  = (float*)(pool + OFF_SG);

    const int tid  = (int)threadIdx.x;
    const int lane = tid & 63;
    const int w    = tid >> 6;       // wave 0..7
    const int q    = lane >> 4;
    const int cl   = lane & 15;

    const int bid = blockIdx.x;
    const int b   = bid >> 5;                 // 32 blocks per batch
    const int myg = (bid >> 3) & 3;
    const int mxg = bid & 7;
    const int my0 = myg * 32;
    const int mx0 = mxg * 16;

    const float sigma = sigma_p[0];
    const float s = __builtin_sqrtf(0.72134752044448170f) / sigma;

    if (tid < 32)      sg[tid] = s * gp[(my0 + tid) * 256 + 1];
    else if (tid < 48) sg[tid] = s * gp[(mx0 + (tid - 32)) * 2];

    // stage x (scaled SoA f32) and y (f16 [ch][k]) for the full K range
    const float2* xb = (const float2*)x_c + (size_t)b * NC;
    const float4* yb = (const float4*)y_c + (size_t)b * NC * 2;
    for (int it = tid; it < NC; it += BLK) {
        const float2 v = xb[it];
        sxt[it] = s * v.x;
        syt[it] = s * v.y;
        const float4 y0 = yb[(size_t)it * 2];
        const float4 y1 = yb[(size_t)it * 2 + 1];
        __fp16* yw = sys + it;
        yw[0 * LDHY] = (__fp16)y0.x;
        yw[1 * LDHY] = (__fp16)y0.y;
        yw[2 * LDHY] = (__fp16)y0.z;
        yw[3 * LDHY] = (__fp16)y0.w;
        yw[4 * LDHY] = (__fp16)y1.x;
        yw[5 * LDHY] = (__fp16)y1.y;
        yw[6 * LDHY] = (__fp16)y1.z;
        yw[7 * LDHY] = (__fp16)y1.w;
    }
    __syncthreads();

    const float sgy0 = sg[cl];         // my-tile 0: rows my0 + cl
    const float sgy1 = sg[16 + cl];    // my-tile 1: rows my0 + 16 + cl
    const float sgxr = sg[32 + cl];    // mx: cols mx0 + cl

    f32x4 acc[2][9];
#pragma unroll
    for (int t = 0; t < 2; ++t)
#pragma unroll
        for (int c = 0; c < 9; ++c) acc[t][c] = (f32x4)0.0f;

    // main loop: wave covers K window [w*KW, (w+1)*KW), 8 steps of 32
    const int kbase = w * KW;
#pragma unroll 2
    for (int ks = 0; ks < KW / 32; ++ks) {
        const int kq = kbase + ks * 32 + q * 8;

        const f32x4 ya0 = *(const f32x4*)(syt + kq);
        const f32x4 ya1 = *(const f32x4*)(syt + kq + 4);
        const f32x4 xa0 = *(const f32x4*)(sxt + kq);
        const f32x4 xa1 = *(const f32x4*)(sxt + kq + 4);

        // A-fragment wy for my-tile 0
        const f32x4 y0e0 = ya0 - sgy0, y0e1 = ya1 - sgy0;
        const f32x4 y0m0 = y0e0 * y0e0, y0m1 = y0e1 * y0e1;
        const half2t p00 = __builtin_amdgcn_cvt_pkrtz(
            __builtin_amdgcn_exp2f(-y0m0.x), __builtin_amdgcn_exp2f(-y0m0.y));
        const half2t p01 = __builtin_amdgcn_cvt_pkrtz(
            __builtin_amdgcn_exp2f(-y0m0.z), __builtin_amdgcn_exp2f(-y0m0.w));
        const half2t p02 = __builtin_amdgcn_cvt_pkrtz(
            __builtin_amdgcn_exp2f(-y0m1.x), __builtin_amdgcn_exp2f(-y0m1.y));
        const half2t p03 = __builtin_amdgcn_cvt_pkrtz(
            __builtin_amdgcn_exp2f(-y0m1.z), __builtin_amdgcn_exp2f(-y0m1.w));
        const half8 af0 = (half8){p00.x, p00.y, p01.x, p01.y, p02.x, p02.y, p03.x, p03.y};

        // A-fragment wy for my-tile 1
        const f32x4 y1e0 = ya0 - sgy1, y1e1 = ya1 - sgy1;
        const f32x4 y1m0 = y1e0 * y1e0, y1m1 = y1e1 * y1e1;
        const half2t p10 = __builtin_amdgcn_cvt_pkrtz(
            __builtin_amdgcn_exp2f(-y1m0.x), __builtin_amdgcn_exp2f(-y1m0.y));
        const half2t p11 = __builtin_amdgcn_cvt_pkrtz(
            __builtin_amdgcn_exp2f(-y1m0.z), __builtin_amdgcn_exp2f(-y1m0.w));
        const half2t p12 = __builtin_amdgcn_cvt_pkrtz(
            __builtin_amdgcn_exp2f(-y1m1.x), __builtin_amdgcn_exp2f(-y1m1.y));
        const half2t p13 = __builtin_amdgcn_cvt_pkrtz(
            __builtin_amdgcn_exp2f(-y1m1.z), __builtin_amdgcn_exp2f(-y1m1.w));
        const half8 af1 = (half8){p10.x, p10.y, p11.x, p11.y, p12.x, p12.y, p13.x, p13.y};

        // B-fragment wx (shared across both my-tiles)
        const f32x4 xe0 = xa0 - sgxr, xe1 = xa1 - sgxr;
        const f32x4 xm0 = xe0 * xe0,   xm1 = xe1 * xe1;
        const half2t b0 = __builtin_amdgcn_cvt_pkrtz(
            __builtin_amdgcn_exp2f(-xm0.x), __builtin_amdgcn_exp2f(-xm0.y));
        const half2t b1 = __builtin_amdgcn_cvt_pkrtz(
            __builtin_amdgcn_exp2f(-xm0.z), __builtin_amdgcn_exp2f(-xm0.w));
        const half2t b2 = __builtin_amdgcn_cvt_pkrtz(
            __builtin_amdgcn_exp2f(-xm1.x), __builtin_amdgcn_exp2f(-xm1.y));
        const half2t b3 = __builtin_amdgcn_cvt_pkrtz(
            __builtin_amdgcn_exp2f(-xm1.z), __builtin_amdgcn_exp2f(-xm1.w));
        const half8 bx = (half8){b0.x, b0.y, b1.x, b1.y, b2.x, b2.y, b3.x, b3.y};

        acc[0][0] = __builtin_amdgcn_mfma_f32_16x16x32_f16(af0, bx, acc[0][0], 0, 0, 0);
        acc[1][0] = __builtin_amdgcn_mfma_f32_16x16x32_f16(af1, bx, acc[1][0], 0, 0, 0);
        const __fp16* yp = sys + kq;
#pragma unroll
        for (int c = 0; c < 8; ++c) {
            const half8 yf  = *(const half8*)(yp + c * LDHY);
            const half8 bxy = bx * yf;   // shared for both tiles
            acc[0][c + 1] = __builtin_amdgcn_mfma_f32_16x16x32_f16(af0, bxy, acc[0][c + 1], 0, 0, 0);
            acc[1][c + 1] = __builtin_amdgcn_mfma_f32_16x16x32_f16(af1, bxy, acc[1][c + 1], 0, 0, 0);
        }
    }

    // ---- flat reduce: slot_s = acc_{s+4} + acc_s; final = (s0+s1)+(s2+s3) ----
    __syncthreads();                       // tiles dead; alias slot bufs
    float* slots = (float*)pool;           // [4][2][9][256]
    if (w >= 4) {
        float* rb = slots + (w - 4) * SLOT_F;
#pragma unroll
        for (int t = 0; t < 2; ++t)
#pragma unroll
            for (int c = 0; c < 9; ++c)
#pragma unroll
                for (int r = 0; r < 4; ++r)
                    rb[t * 2304 + c * 256 + (q * 4 + r) * 16 + cl] = acc[t][c][r];
    }
    __syncthreads();
    if (w < 4) {
        float* rb = slots + w * SLOT_F;
#pragma unroll
        for (int t = 0; t < 2; ++t)
#pragma unroll
            for (int c = 0; c < 9; ++c)
#pragma unroll
                for (int r = 0; r < 4; ++r) {
                    const int idx = t * 2304 + c * 256 + (q * 4 + r) * 16 + cl;
                    rb[idx] = rb[idx] + acc[t][c][r];   // acc_{w+4} + acc_w
                }
    }
    __syncthreads();

    // final 4-way sum + normalize + store: thread -> (t, my, mx), 512 total
    {
        float* ob = out + (size_t)b * 9 * M_;
        const int t  = tid >> 8;
        const int my = (tid >> 4) & 15;
        const int mx = tid & 15;
        const size_t mo = (size_t)(my0 + t * 16 + my) * 128 + mx0 + mx;
        float v[9];
#pragma unroll
        for (int c = 0; c < 9; ++c) {
            const int idx = t * 2304 + c * 256 + my * 16 + mx;
            v[c] = (slots[idx] + slots[SLOT_F + idx]) +
                   (slots[2 * SLOT_F + idx] + slots[3 * SLOT_F + idx]);
        }
        const float inv = __builtin_amdgcn_rcpf(v[0] + 1e-5f);
        ob[mo] = v[0];
#pragma unroll
        for (int c = 1; c < 9; ++c)
            ob[(size_t)c * M_ + mo] = v[c] * inv;
    }
}

extern "C" void kernel_launch(void* const* d_in, const int* in_sizes, int n_in,
                              void* d_out, int out_size, void* d_ws, size_t ws_size,
                              hipStream_t stream) {
    const float* x_c   = (const float*)d_in[0];
    const float* y_c   = (const float*)d_in[1];
    const float* gp    = (const float*)d_in[2];
    const float* sigma = (const float*)d_in[3];
    float* out = (float*)d_out;

    dim3 grid(B_ * 32);      // 256 blocks: 8 batches x 4 my-groups x 8 mx-groups
    dim3 block(BLK);
    rbf_sep<<<grid, block, 0, stream>>>(x_c, y_c, gp, sigma, out);
}